// Round 1
// baseline (4671.195 us; speedup 1.0000x reference)
//
#include <hip/hip_runtime.h>

// ---------------------------------------------------------------------------
// FrontierVerifierExpertHead — fp32 baseline, MI355X (gfx950)
// Structure: precompute collapsed attention matrices; 6-step recurrent loop
// with factorized per-item memory bank; fused expert up->down with atomic
// 10-wide accumulation; per-item router/top-k; final combine.
// ---------------------------------------------------------------------------

constexpr int NI      = 4096;   // items
constexpr int DIM     = 256;
constexpr int ODIM    = 10;
constexpr int NMEM_   = 32;
constexpr int NSTEPS_ = 6;
constexpr int NEXPERT_= 12;
constexpr int MAXE    = 4608;
#define SCL 0.0625f             // 256^-0.5

__constant__ int EDIMS[NEXPERT_] = {2048,2560,3072,3584,4096,2304,2816,3328,3840,4608,3072,4096};

// ----------------------------- device helpers ------------------------------

__device__ __forceinline__ float wred_sum(float v){
  #pragma unroll
  for (int m = 32; m > 0; m >>= 1) v += __shfl_xor(v, m, 64);
  return v;
}
__device__ __forceinline__ float wred_max(float v){
  #pragma unroll
  for (int m = 32; m > 0; m >>= 1) v = fmaxf(v, __shfl_xor(v, m, 64));
  return v;
}
__device__ __forceinline__ float sigm(float x){ return 1.f/(1.f+expf(-x)); }
__device__ __forceinline__ float geluf(float x){ return 0.5f*x*(1.f+erff(x*0.70710678118654752f)); }
__device__ __forceinline__ float softplusf(float x){ return fmaxf(x,0.f) + log1pf(expf(-fabsf(x))); }
__device__ __forceinline__ float act_apply(int a, float x){
  switch(a){
    case 0: return x*sigm(x);                         // silu
    case 1: return geluf(x);                          // gelu (exact)
    case 2: return x*tanhf(softplusf(x));             // mish
    case 3: return fmaxf(x,0.f);                      // relu
    case 4: { const float l=1.0507009873554805f, al=1.6732632423543772f;
              return x>0.f ? l*x : l*al*expm1f(x); }  // selu
    case 5: return tanhf(x);                          // tanh
    case 6: return softplusf(x);                      // softplus
    default: return x>0.f ? x : expm1f(x);            // elu
  }
}
__device__ __forceinline__ void ln10(const float* p, const float* s, const float* b, float* o){
  float mu = 0.f;
  #pragma unroll
  for (int i=0;i<ODIM;i++) mu += p[i];
  mu *= 0.1f;
  float var = 0.f;
  #pragma unroll
  for (int i=0;i<ODIM;i++){ float d = p[i]-mu; var += d*d; }
  var *= 0.1f;
  float rs = 1.f/sqrtf(var + 1e-5f);
  #pragma unroll
  for (int i=0;i<ODIM;i++) o[i] = (p[i]-mu)*rs*s[i] + b[i];
}

// ----------------------------- tiled fp32 GEMM -----------------------------
// C[4096,N] = epi(A[4096,K] @ W[N,K]^T)
// EPI: 0 none | 1 +bias | 2 gelu(+bias) | 3 +bias+R | 4 tanh(acc)*sig(vec[c]) | 5 +R
template<int EPI>
__global__ __launch_bounds__(256)
void gemm_k(const float* __restrict__ A, const float* __restrict__ W,
            const float* __restrict__ bias, const float* __restrict__ R,
            const float* __restrict__ vec, float* __restrict__ C,
            int N, int K)
{
  __shared__ float As[32][68];
  __shared__ float Ws[32][68];
  const int bm = blockIdx.y*64, bn = blockIdx.x*64;
  const int tid = threadIdx.x;
  const int tx = tid & 15, ty = tid >> 4;
  const int lrow = tid >> 2, lkq = (tid & 3) * 8;
  float acc[4][4] = {};
  for (int k0 = 0; k0 < K; k0 += 32){
    #pragma unroll
    for (int h = 0; h < 2; ++h){
      int kk = lkq + h*4;
      float4 va = make_float4(0.f,0.f,0.f,0.f), vw = make_float4(0.f,0.f,0.f,0.f);
      if (k0 + kk < K)
        va = *(const float4*)&A[(size_t)(bm+lrow)*K + k0 + kk];
      if (bn + lrow < N && k0 + kk < K)
        vw = *(const float4*)&W[(size_t)(bn+lrow)*K + k0 + kk];
      As[kk+0][lrow]=va.x; As[kk+1][lrow]=va.y; As[kk+2][lrow]=va.z; As[kk+3][lrow]=va.w;
      Ws[kk+0][lrow]=vw.x; Ws[kk+1][lrow]=vw.y; Ws[kk+2][lrow]=vw.z; Ws[kk+3][lrow]=vw.w;
    }
    __syncthreads();
    #pragma unroll
    for (int kk = 0; kk < 32; ++kk){
      float4 a4 = *(const float4*)&As[kk][ty*4];
      float4 b4 = *(const float4*)&Ws[kk][tx*4];
      float av[4] = {a4.x,a4.y,a4.z,a4.w};
      float bv[4] = {b4.x,b4.y,b4.z,b4.w};
      #pragma unroll
      for (int i=0;i<4;i++)
        #pragma unroll
        for (int j=0;j<4;j++) acc[i][j] = fmaf(av[i], bv[j], acc[i][j]);
    }
    __syncthreads();
  }
  #pragma unroll
  for (int i=0;i<4;i++){
    int r = bm + ty*4 + i;
    #pragma unroll
    for (int j=0;j<4;j++){
      int c = bn + tx*4 + j;
      if (c >= N) continue;
      float v = acc[i][j];
      if constexpr (EPI==1) v += bias[c];
      else if constexpr (EPI==2) v = geluf(v + bias[c]);
      else if constexpr (EPI==3) v = v + bias[c] + R[(size_t)r*N + c];
      else if constexpr (EPI==4) v = tanhf(v) * sigm(vec[c]);
      else if constexpr (EPI==5) v = v + R[(size_t)r*N + c];
      C[(size_t)r*N + c] = v;
    }
  }
}

// --------------------- fused up->down (shared/aux/experts) -----------------
// h = act(X[64rows] @ up[64cols,256]^T); out10[row] += h @ down_slice^T
__device__ __forceinline__ void updown_body(
    const float* __restrict__ X, const float* __restrict__ up,
    const float* __restrict__ down, int downStride,
    float* __restrict__ out10, int ebase, int act)
{
  __shared__ float As[32][68];
  __shared__ float Us[32][68];
  __shared__ float ds[ODIM][64];
  const int bm = blockIdx.y*64;
  const int tid = threadIdx.x;
  const int tx = tid & 15, ty = tid >> 4;
  const int lrow = tid >> 2, lkq = (tid & 3) * 8;
  // stage down slice (synced by first k-loop barrier)
  for (int t = tid; t < 64*ODIM; t += 256){
    int o = t >> 6, e = t & 63;
    ds[o][e] = down[(size_t)o*downStride + ebase + e];
  }
  float acc[4][4] = {};
  for (int k0 = 0; k0 < DIM; k0 += 32){
    #pragma unroll
    for (int h = 0; h < 2; ++h){
      int kk = lkq + h*4;
      float4 va = *(const float4*)&X[(size_t)(bm+lrow)*DIM + k0 + kk];
      float4 vu = *(const float4*)&up[(size_t)(ebase+lrow)*DIM + k0 + kk];
      As[kk+0][lrow]=va.x; As[kk+1][lrow]=va.y; As[kk+2][lrow]=va.z; As[kk+3][lrow]=va.w;
      Us[kk+0][lrow]=vu.x; Us[kk+1][lrow]=vu.y; Us[kk+2][lrow]=vu.z; Us[kk+3][lrow]=vu.w;
    }
    __syncthreads();
    #pragma unroll
    for (int kk = 0; kk < 32; ++kk){
      float4 a4 = *(const float4*)&As[kk][ty*4];
      float4 b4 = *(const float4*)&Us[kk][tx*4];
      float av[4] = {a4.x,a4.y,a4.z,a4.w};
      float bv[4] = {b4.x,b4.y,b4.z,b4.w};
      #pragma unroll
      for (int i=0;i<4;i++)
        #pragma unroll
        for (int j=0;j<4;j++) acc[i][j] = fmaf(av[i], bv[j], acc[i][j]);
    }
    __syncthreads();
  }
  #pragma unroll
  for (int i=0;i<4;i++){
    float hv[4];
    #pragma unroll
    for (int j=0;j<4;j++) hv[j] = act_apply(act, acc[i][j]);
    #pragma unroll
    for (int o=0;o<ODIM;o++){
      float s = 0.f;
      #pragma unroll
      for (int j=0;j<4;j++) s = fmaf(hv[j], ds[o][tx*4+j], s);
      // reduce across the 16 tx lanes of this ty group
      s += __shfl_xor(s,1,64); s += __shfl_xor(s,2,64);
      s += __shfl_xor(s,4,64); s += __shfl_xor(s,8,64);
      if (tx == 0)
        atomicAdd(&out10[(size_t)(bm + ty*4 + i)*ODIM + o], s);
    }
  }
}

__global__ __launch_bounds__(256)
void updown_k(const float* __restrict__ X, const float* __restrict__ up,
              const float* __restrict__ down, float* __restrict__ out10,
              int E, int act)
{
  updown_body(X, up, down, E, out10, blockIdx.x*64, act);
}

__global__ __launch_bounds__(256)
void experts_k(const float* __restrict__ X, const float* __restrict__ upAll,
               const float* __restrict__ downAll, float* __restrict__ preAll)
{
  const int ex = blockIdx.z;
  const int E = EDIMS[ex];
  const int ebase = blockIdx.x*64;
  if (ebase >= E) return;
  updown_body(X, upAll + (size_t)ex*MAXE*DIM, downAll + (size_t)ex*ODIM*MAXE, MAXE,
              preAll + (size_t)ex*NI*ODIM, ebase, ex & 7);
}

// --------------------------- thin per-element GEMM -------------------------
// C[n,NO] = post(A1@W[:, :K1]^T + A2@W[:, K1:]^T + bias); post: 0 none,1 sigmoid,2 *SCL
__global__ __launch_bounds__(256)
void thin_k(const float* __restrict__ A1, int K1,
            const float* __restrict__ A2, int K2,
            const float* __restrict__ W, const float* __restrict__ bias,
            float* __restrict__ C, int NO, int post)
{
  int idx = blockIdx.x*256 + threadIdx.x;
  if (idx >= NI*NO) return;
  int item = idx / NO, o = idx - item*NO;
  const float* w = W + (size_t)o*(K1+K2);
  const float* a1 = A1 + (size_t)item*K1;
  float s = 0.f;
  for (int k = 0; k < K1; k += 4){
    float4 av = *(const float4*)&a1[k];
    float4 wv = *(const float4*)&w[k];
    s = fmaf(av.x,wv.x, fmaf(av.y,wv.y, fmaf(av.z,wv.z, fmaf(av.w,wv.w, s))));
  }
  if (A2){
    const float* a2 = A2 + (size_t)item*K2;
    const float* w2 = w + K1;
    for (int k = 0; k < K2; k += 4){
      float4 av = *(const float4*)&a2[k];
      float4 wv = *(const float4*)&w2[k];
      s = fmaf(av.x,wv.x, fmaf(av.y,wv.y, fmaf(av.z,wv.z, fmaf(av.w,wv.w, s))));
    }
  }
  if (bias) s += bias[o];
  if (post == 1) s = sigm(s);
  else if (post == 2) s *= SCL;
  C[(size_t)item*NO + o] = s;
}

// ----------------------- small one-off matrix products ---------------------
__global__ void atb_k(const float* __restrict__ A, const float* __restrict__ B,
                      float* __restrict__ C, int M, int I, int J)
{ // C[i,j] = sum_m A[m,i]*B[m,j]
  int idx = blockIdx.x*256 + threadIdx.x;
  if (idx >= I*J) return;
  int i = idx / J, j = idx - i*J;
  float s = 0.f;
  for (int m = 0; m < M; m++) s = fmaf(A[(size_t)m*I+i], B[(size_t)m*J+j], s);
  C[idx] = s;
}
__global__ void ab_k(const float* __restrict__ A, const float* __restrict__ B,
                     float* __restrict__ C, int M, int K, int N)
{ // C[i,j] = sum_k A[i,k]*B[k,j]
  int idx = blockIdx.x*256 + threadIdx.x;
  if (idx >= M*N) return;
  int i = idx / N, j = idx - i*N;
  float s = 0.f;
  for (int k = 0; k < K; k++) s = fmaf(A[(size_t)i*K+k], B[(size_t)k*N+j], s);
  C[idx] = s;
}

// --------------------- LN (+up to 2 extra addends), D=256 ------------------
__global__ __launch_bounds__(256)
void ln3_k(const float* __restrict__ a, const float* __restrict__ b,
           const float* __restrict__ c, const float* __restrict__ lns,
           const float* __restrict__ lnb, float* __restrict__ xout,
           float* __restrict__ lnout)
{
  int item = blockIdx.x*4 + (threadIdx.x >> 6);
  int lane = threadIdx.x & 63;
  float4 v = ((const float4*)(a + (size_t)item*DIM))[lane];
  if (b){ float4 t = ((const float4*)(b + (size_t)item*DIM))[lane]; v.x+=t.x; v.y+=t.y; v.z+=t.z; v.w+=t.w; }
  if (c){ float4 t = ((const float4*)(c + (size_t)item*DIM))[lane]; v.x+=t.x; v.y+=t.y; v.z+=t.z; v.w+=t.w; }
  if (xout) ((float4*)(xout + (size_t)item*DIM))[lane] = v;
  float mu = wred_sum(v.x+v.y+v.z+v.w) * (1.f/DIM);
  float dx=v.x-mu, dy=v.y-mu, dz=v.z-mu, dw=v.w-mu;
  float var = wred_sum(dx*dx+dy*dy+dz*dz+dw*dw) * (1.f/DIM);
  float rs = 1.f/sqrtf(var + 1e-5f);
  float4 s4 = ((const float4*)lns)[lane];
  float4 b4 = ((const float4*)lnb)[lane];
  float4 o4 = make_float4(dx*rs*s4.x + b4.x, dy*rs*s4.y + b4.y,
                          dz*rs*s4.z + b4.z, dw*rs*s4.w + b4.w);
  ((float4*)(lnout + (size_t)item*DIM))[lane] = o4;
}

// -------------------- memory read (factorized bank state) ------------------
__global__ __launch_bounds__(256)
void memread_k(const float* __restrict__ sc, const float* __restrict__ a_state,
               const float* __restrict__ c_state, const float* __restrict__ mem_vals,
               const float* __restrict__ wv_hist, float* __restrict__ mem_read, int step)
{
  int item = blockIdx.x*4 + (threadIdx.x >> 6);
  int lane = threadIdx.x & 63;
  float v = (lane < NMEM_) ? sc[(size_t)item*NMEM_ + lane] : -1e30f;
  float m = wred_max(v);
  float e = (lane < NMEM_) ? expf(v - m) : 0.f;
  float inv = 1.f / wred_sum(e);
  float attn = e * inv;
  float aval = 0.f;
  if (lane < NMEM_) aval = (step == 0) ? 1.f : a_state[(size_t)item*NMEM_ + lane];
  float wslot = attn * aval;
  float beta[NSTEPS_];
  #pragma unroll
  for (int t = 0; t < NSTEPS_; t++){
    beta[t] = 0.f;
    if (t < step){
      float cc = (lane < NMEM_) ? c_state[((size_t)item*NMEM_ + lane)*NSTEPS_ + t] : 0.f;
      beta[t] = wred_sum(attn * cc);
    }
  }
  float ax=0.f, ay=0.f, az=0.f, aw=0.f;
  #pragma unroll
  for (int s2 = 0; s2 < NMEM_; s2++){
    float ws = __shfl(wslot, s2, 64);
    float4 mv = ((const float4*)(mem_vals + (size_t)s2*DIM))[lane];
    ax = fmaf(ws, mv.x, ax); ay = fmaf(ws, mv.y, ay);
    az = fmaf(ws, mv.z, az); aw = fmaf(ws, mv.w, aw);
  }
  #pragma unroll
  for (int t = 0; t < NSTEPS_; t++){
    if (t < step){
      float4 h4 = ((const float4*)(wv_hist + ((size_t)t*NI + item)*DIM))[lane];
      ax = fmaf(beta[t], h4.x, ax); ay = fmaf(beta[t], h4.y, ay);
      az = fmaf(beta[t], h4.z, az); aw = fmaf(beta[t], h4.w, aw);
    }
  }
  ((float4*)(mem_read + (size_t)item*DIM))[lane] = make_float4(ax,ay,az,aw);
}

// ------------------------- memory state coefficient update -----------------
__global__ void state_k(const float* __restrict__ wg, float* __restrict__ a_state,
                        float* __restrict__ c_state, int step)
{
  int idx = blockIdx.x*256 + threadIdx.x;      // item*32 + slot
  if (idx >= NI*NMEM_) return;
  float g = wg[idx];
  float om = 1.f - g;
  float a = (step == 0) ? 1.f : a_state[idx];
  a_state[idx] = a * om;
  float* c = c_state + (size_t)idx*NSTEPS_;
  #pragma unroll
  for (int t = 0; t < NSTEPS_; t++) if (t < step) c[t] *= om;
  c[step] = g;
}

// ------------------- bank attention (scores+softmax+wsum) ------------------
__global__ __launch_bounds__(256)
void bankattn_k(const float* __restrict__ q2, const float* __restrict__ bank,
                float* __restrict__ wsum, int t)
{
  int item = blockIdx.x*4 + (threadIdx.x >> 6);
  int lane = threadIdx.x & 63;
  float4 q4 = ((const float4*)(q2 + (size_t)item*DIM))[lane];
  float sc[NSTEPS_];
  float4 bb[NSTEPS_];
  #pragma unroll
  for (int j = 0; j < NSTEPS_; j++){
    if (j < t){
      bb[j] = ((const float4*)(bank + ((size_t)j*NI + item)*DIM))[lane];
      sc[j] = wred_sum(q4.x*bb[j].x + q4.y*bb[j].y + q4.z*bb[j].z + q4.w*bb[j].w) * SCL;
    }
  }
  float mx = -1e30f;
  #pragma unroll
  for (int j = 0; j < NSTEPS_; j++) if (j < t) mx = fmaxf(mx, sc[j]);
  float se = 0.f;
  #pragma unroll
  for (int j = 0; j < NSTEPS_; j++) if (j < t){ sc[j] = expf(sc[j]-mx); se += sc[j]; }
  float inv = 1.f/se;
  float ax=0.f, ay=0.f, az=0.f, aw=0.f;
  #pragma unroll
  for (int j = 0; j < NSTEPS_; j++){
    if (j < t){
      float a = sc[j]*inv;
      ax = fmaf(a, bb[j].x, ax); ay = fmaf(a, bb[j].y, ay);
      az = fmaf(a, bb[j].z, az); aw = fmaf(a, bb[j].w, aw);
    }
  }
  ((float4*)(wsum + (size_t)item*DIM))[lane] = make_float4(ax,ay,az,aw);
}

// ----------------- halting + weighted 10-dim logit accumulation ------------
__global__ __launch_bounds__(256)
void halt_k(const float* __restrict__ cur, const float* __restrict__ mem_read,
            const float* __restrict__ depth_ctx, const float* __restrict__ halt_w,
            const float* __restrict__ halt_b, const float* __restrict__ mem_out_w,
            const float* __restrict__ depth_out_w, float* __restrict__ mem_logits,
            float* __restrict__ depth_logits, float* __restrict__ cum_halt, int step)
{
  int item = blockIdx.x*4 + (threadIdx.x >> 6);
  int lane = threadIdx.x & 63;
  float4 c4 = ((const float4*)(cur + (size_t)item*DIM))[lane];
  float4 hw = ((const float4*)(halt_w + (size_t)step*DIM))[lane];
  float hd = wred_sum(c4.x*hw.x + c4.y*hw.y + c4.z*hw.z + c4.w*hw.w);
  float halt = sigm(hd + halt_b[step]);
  float ch = cum_halt[item];
  float wstep = (1.f - ch) * halt;
  float4 m4 = ((const float4*)(mem_read + (size_t)item*DIM))[lane];
  float4 d4 = make_float4(0.f,0.f,0.f,0.f);
  if (step > 0) d4 = ((const float4*)(depth_ctx + (size_t)item*DIM))[lane];
  #pragma unroll
  for (int o = 0; o < ODIM; o++){
    float4 w4 = ((const float4*)(mem_out_w + (size_t)o*DIM))[lane];
    float s = wred_sum(m4.x*w4.x + m4.y*w4.y + m4.z*w4.z + m4.w*w4.w);
    if (lane == 0) mem_logits[(size_t)item*ODIM + o] += wstep * s;
    if (step > 0){
      float4 v4 = ((const float4*)(depth_out_w + (size_t)o*DIM))[lane];
      float s2 = wred_sum(d4.x*v4.x + d4.y*v4.y + d4.z*v4.z + d4.w*v4.w);
      if (lane == 0) depth_logits[(size_t)item*ODIM + o] += wstep * s2;
    }
  }
  if (lane == 0) cum_halt[item] = fminf(ch + halt, 1.f);
}

// -------------------------- router finish (per item) -----------------------
__global__ void router_k(const float* __restrict__ sub60, const float* __restrict__ gate5,
                         const float* __restrict__ budget5, float* __restrict__ sparse)
{
  int item = blockIdx.x*256 + threadIdx.x;
  if (item >= NI) return;
  float probs[NEXPERT_];
  #pragma unroll
  for (int e = 0; e < NEXPERT_; e++) probs[e] = 0.f;
  // gate softmax (5)
  float g[5];
  float gm = -1e30f;
  #pragma unroll
  for (int s = 0; s < 5; s++){ g[s] = gate5[(size_t)item*5 + s]; gm = fmaxf(gm, g[s]); }
  float gs = 0.f;
  #pragma unroll
  for (int s = 0; s < 5; s++){ g[s] = expf(g[s]-gm); gs += g[s]; }
  float gi = 1.f/gs;
  // per-sub softmax over 12 experts, mix by gate
  #pragma unroll
  for (int s = 0; s < 5; s++){
    float sl[NEXPERT_];
    float mx = -1e30f;
    #pragma unroll
    for (int e = 0; e < NEXPERT_; e++){ sl[e] = sub60[(size_t)item*60 + s*NEXPERT_ + e]; mx = fmaxf(mx, sl[e]); }
    float se = 0.f;
    #pragma unroll
    for (int e = 0; e < NEXPERT_; e++){ sl[e] = expf(sl[e]-mx); se += sl[e]; }
    float w = g[s]*gi/se;
    #pragma unroll
    for (int e = 0; e < NEXPERT_; e++) probs[e] = fmaf(w, sl[e], probs[e]);
  }
  // budget argmax -> active_k
  float bl0 = budget5[(size_t)item*5];
  int am = 0;
  #pragma unroll
  for (int s = 1; s < 5; s++){ float bv = budget5[(size_t)item*5 + s]; if (bv > bl0){ bl0 = bv; am = s; } }
  int kact = am + 1;
  // top-5 (descending, stable)
  unsigned used = 0;
  float tv[5]; int ti[5];
  float ssum = 0.f;
  #pragma unroll
  for (int j = 0; j < 5; j++){
    float bv = -1e30f; int bi = 0;
    #pragma unroll
    for (int e = 0; e < NEXPERT_; e++){
      bool ok = !((used >> e) & 1u);
      if (ok && probs[e] > bv){ bv = probs[e]; bi = e; }
    }
    used |= (1u << bi);
    tv[j] = bv; ti[j] = bi;
    if (j < kact) ssum += bv;
  }
  float den = 1.f/fmaxf(ssum, 1e-6f);
  #pragma unroll
  for (int e = 0; e < NEXPERT_; e++){
    float v = 0.f;
    #pragma unroll
    for (int j = 0; j < 5; j++) if (j < kact && ti[j] == e) v = tv[j];
    sparse[(size_t)item*NEXPERT_ + e] = v*den;
  }
}

// ------------------------------ final combine ------------------------------
__global__ void final_k(
  const float* __restrict__ x, const float* __restrict__ cur,
  const float* __restrict__ vbuf, const float* __restrict__ coll_ctx,
  const float* __restrict__ ver_ctx,
  const float* __restrict__ base10, const float* __restrict__ shared_pre,
  const float* __restrict__ aux_pre, const float* __restrict__ expert_pre,
  const float* __restrict__ sparse, const float* __restrict__ mem_logits,
  const float* __restrict__ depth_logits, const float* __restrict__ reflect10,
  const float* __restrict__ coll10, const float* __restrict__ ver10,
  const float* __restrict__ corr10,
  const float* __restrict__ shared_ln_s, const float* __restrict__ shared_ln_b,
  const float* __restrict__ aux_ln_s, const float* __restrict__ aux_ln_b,
  const float* __restrict__ exp_ln_s, const float* __restrict__ exp_ln_b,
  const float* __restrict__ aux_gate_w, const float* __restrict__ aux_gate_b,
  const float* __restrict__ ver_gate_w, const float* __restrict__ ver_gate_b,
  const float* __restrict__ revisit_w, const float* __restrict__ revisit_b,
  const float* __restrict__ shared_scale, const float* __restrict__ mix,
  float* __restrict__ out)
{
  int item = blockIdx.x*256 + threadIdx.x;
  if (item >= NI) return;
  const float* xr = x + (size_t)item*DIM;
  const float* cr = cur + (size_t)item*DIM;
  const float* vr = vbuf + (size_t)item*DIM;
  const float* lr = coll_ctx + (size_t)item*DIM;
  const float* tr = ver_ctx + (size_t)item*DIM;
  // ag softmax(2) over x
  float ag0 = aux_gate_b[0], ag1 = aux_gate_b[1];
  for (int k = 0; k < DIM; k++){
    float xv = xr[k];
    ag0 = fmaf(xv, aux_gate_w[k], ag0);
    ag1 = fmaf(xv, aux_gate_w[DIM+k], ag1);
  }
  { float m = fmaxf(ag0,ag1); float e0 = expf(ag0-m), e1 = expf(ag1-m);
    float i2 = 1.f/(e0+e1); ag0 = e0*i2; ag1 = e1*i2; }
  // vg softmax(2) over [v, ver_ctx]
  float vg0 = ver_gate_b[0], vg1 = ver_gate_b[1];
  for (int k = 0; k < DIM; k++){
    vg0 = fmaf(vr[k], ver_gate_w[k], vg0);
    vg1 = fmaf(vr[k], ver_gate_w[512+k], vg1);
  }
  for (int k = 0; k < DIM; k++){
    vg0 = fmaf(tr[k], ver_gate_w[DIM+k], vg0);
    vg1 = fmaf(tr[k], ver_gate_w[512+DIM+k], vg1);
  }
  { float m = fmaxf(vg0,vg1); float e0 = expf(vg0-m), e1 = expf(vg1-m);
    float i2 = 1.f/(e0+e1); vg0 = e0*i2; vg1 = e1*i2; }
  // revisit gate
  float rv = revisit_b[0];
  for (int k = 0; k < DIM; k++){
    rv = fmaf(xr[k], revisit_w[k], rv);
    rv = fmaf(cr[k], revisit_w[DIM+k], rv);
    rv = fmaf(lr[k], revisit_w[2*DIM+k], rv);
  }
  rv = sigm(rv);
  // shared / aux LN over 10
  float sh[ODIM], axl[ODIM];
  { float tmp[ODIM];
    #pragma unroll
    for (int o = 0; o < ODIM; o++) tmp[o] = shared_pre[(size_t)item*ODIM + o];
    ln10(tmp, shared_ln_s, shared_ln_b, sh);
    #pragma unroll
    for (int o = 0; o < ODIM; o++) tmp[o] = aux_pre[(size_t)item*ODIM + o];
    ln10(tmp, aux_ln_s, aux_ln_b, axl); }
  // experts: LN each + sparse-weighted sum
  float eo[ODIM];
  #pragma unroll
  for (int o = 0; o < ODIM; o++) eo[o] = 0.f;
  for (int i2 = 0; i2 < NEXPERT_; i2++){
    float sp = sparse[(size_t)item*NEXPERT_ + i2];
    if (sp != 0.f){
      float tmp[ODIM], lo[ODIM];
      #pragma unroll
      for (int o = 0; o < ODIM; o++) tmp[o] = expert_pre[((size_t)i2*NI + item)*ODIM + o];
      ln10(tmp, exp_ln_s + i2*ODIM, exp_ln_b + i2*ODIM, lo);
      #pragma unroll
      for (int o = 0; o < ODIM; o++) eo[o] = fmaf(sp, lo[o], eo[o]);
    }
  }
  float al = tanhf(mix[0]), be = tanhf(mix[1]), ga = tanhf(mix[2]);
  float de = tanhf(mix[3]), ep = tanhf(mix[4]), ze = tanhf(mix[5]);
  float ss = shared_scale[0];
  #pragma unroll
  for (int o = 0; o < ODIM; o++){
    size_t ix = (size_t)item*ODIM + o;
    float v = base10[ix]
      + ss*(ag0*sh[o] + ag1*axl[o])
      + al*eo[o]
      + be*mem_logits[ix] + ze*depth_logits[ix]
      + ga*reflect10[ix]
      + de*rv*coll10[ix]
      + ep*(vg0*ver10[ix] + vg1*corr10[ix]);
    out[ix] = v;
  }
}

// ------------------------------- host side ---------------------------------

static void launch_gemm(int epi, const float* A, const float* W, const float* b,
                        const float* R, const float* vec, float* C, int N, int K,
                        hipStream_t stream)
{
  dim3 g((N+63)/64, NI/64), blk(256);
  switch(epi){
    case 0: gemm_k<0><<<g,blk,0,stream>>>(A,W,b,R,vec,C,N,K); break;
    case 1: gemm_k<1><<<g,blk,0,stream>>>(A,W,b,R,vec,C,N,K); break;
    case 2: gemm_k<2><<<g,blk,0,stream>>>(A,W,b,R,vec,C,N,K); break;
    case 3: gemm_k<3><<<g,blk,0,stream>>>(A,W,b,R,vec,C,N,K); break;
    case 4: gemm_k<4><<<g,blk,0,stream>>>(A,W,b,R,vec,C,N,K); break;
    case 5: gemm_k<5><<<g,blk,0,stream>>>(A,W,b,R,vec,C,N,K); break;
  }
}

extern "C" void kernel_launch(void* const* d_in, const int* in_sizes, int n_in,
                              void* d_out, int out_size, void* d_ws, size_t ws_size,
                              hipStream_t stream)
{
  (void)in_sizes; (void)n_in; (void)out_size; (void)ws_size;
  const float* x             = (const float*)d_in[0];
  const float* Wm            = (const float*)d_in[1];
  const float* bvec          = (const float*)d_in[2];
  const float* shared_up_w   = (const float*)d_in[3];
  const float* shared_down_w = (const float*)d_in[4];
  const float* shared_ln_s   = (const float*)d_in[5];
  const float* shared_ln_b   = (const float*)d_in[6];
  const float* shared_scale  = (const float*)d_in[7];
  const float* mem_keys      = (const float*)d_in[8];
  const float* mem_vals      = (const float*)d_in[9];
  const float* mem_q_w       = (const float*)d_in[10];
  const float* mem_out_w     = (const float*)d_in[11];
  const float* mem_wg_w      = (const float*)d_in[12];
  const float* mem_wg_b      = (const float*)d_in[13];
  const float* mem_wv_w      = (const float*)d_in[14];
  const float* mem_wv_b      = (const float*)d_in[15];
  const float* depth_q_w     = (const float*)d_in[16];
  const float* depth_k_w     = (const float*)d_in[17];
  const float* depth_v_w     = (const float*)d_in[18];
  const float* depth_out_w   = (const float*)d_in[19];
  const float* rc_ln_s       = (const float*)d_in[20];
  const float* rc_ln_b       = (const float*)d_in[21];
  const float* rc_w1         = (const float*)d_in[22];
  const float* rc_b1         = (const float*)d_in[23];
  const float* rc_w2         = (const float*)d_in[24];
  const float* rc_b2         = (const float*)d_in[25];
  const float* ssm_in_w      = (const float*)d_in[26];
  const float* ssm_out_w     = (const float*)d_in[27];
  const float* ssm_decay     = (const float*)d_in[28];
  const float* sub_w         = (const float*)d_in[29];
  const float* sub_b         = (const float*)d_in[30];
  const float* gate_w        = (const float*)d_in[31];
  const float* gate_b        = (const float*)d_in[32];
  const float* budget_w      = (const float*)d_in[33];
  const float* budget_b      = (const float*)d_in[34];
  const float* halt_w        = (const float*)d_in[35];
  const float* halt_b        = (const float*)d_in[36];
  const float* aux_up_w      = (const float*)d_in[37];
  const float* aux_down_w    = (const float*)d_in[38];
  const float* aux_ln_s      = (const float*)d_in[39];
  const float* aux_ln_b      = (const float*)d_in[40];
  const float* aux_gate_w    = (const float*)d_in[41];
  const float* aux_gate_b    = (const float*)d_in[42];
  const float* rf_ln_s       = (const float*)d_in[43];
  const float* rf_ln_b       = (const float*)d_in[44];
  const float* rf_w1         = (const float*)d_in[45];
  const float* rf_b1         = (const float*)d_in[46];
  const float* rf_w2         = (const float*)d_in[47];
  const float* rf_b2         = (const float*)d_in[48];
  const float* reflect_out_w = (const float*)d_in[49];
  const float* coll_q_w      = (const float*)d_in[50];
  const float* coll_k_w      = (const float*)d_in[51];
  const float* coll_v_w      = (const float*)d_in[52];
  const float* coll_out_w    = (const float*)d_in[53];
  const float* revisit_w     = (const float*)d_in[54];
  const float* revisit_b     = (const float*)d_in[55];
  const float* vc_ln_s       = (const float*)d_in[56];
  const float* vc_ln_b       = (const float*)d_in[57];
  const float* vc_w1         = (const float*)d_in[58];
  const float* vc_b1         = (const float*)d_in[59];
  const float* vc_w2         = (const float*)d_in[60];
  const float* vc_b2         = (const float*)d_in[61];
  const float* ver_q_w       = (const float*)d_in[62];
  const float* ver_k_w       = (const float*)d_in[63];
  const float* ver_v_w       = (const float*)d_in[64];
  const float* ver_out_w     = (const float*)d_in[65];
  const float* ver_gate_w    = (const float*)d_in[66];
  const float* ver_gate_b    = (const float*)d_in[67];
  const float* correction_out_w = (const float*)d_in[68];
  const float* mix           = (const float*)d_in[69];
  const float* exp_up        = (const float*)d_in[70];
  const float* exp_down      = (const float*)d_in[71];
  const float* exp_ln_s      = (const float*)d_in[72];
  const float* exp_ln_b      = (const float*)d_in[73];
  float* out = (float*)d_out;

  // ---- workspace layout (fp32) ----
  float* w = (float*)d_ws;
  size_t off = 0;
  auto WS = [&](size_t nf){ float* p = w + off; off += nf; return p; };
  float* bank      = WS((size_t)NSTEPS_*NI*DIM);
  float* cur_in    = WS((size_t)NI*DIM);
  float* t_ln      = WS((size_t)NI*DIM);
  float* hbig      = WS((size_t)NI*1536);
  float* mem_read  = WS((size_t)NI*DIM);
  float* depth_ctx = WS((size_t)NI*DIM);
  float* q2        = WS((size_t)NI*DIM);
  float* wsumb     = WS((size_t)NI*DIM);
  float* wv_hist   = WS((size_t)NSTEPS_*NI*DIM);
  float* wg        = WS((size_t)NI*NMEM_);
  float* mem_sc    = WS((size_t)NI*NMEM_);
  float* a_state   = WS((size_t)NI*NMEM_);
  float* c_state   = WS((size_t)NI*NMEM_*NSTEPS_);
  float* h48       = WS((size_t)NI*48);
  float* rbuf      = WS((size_t)NI*DIM);
  float* vbuf      = WS((size_t)NI*DIM);
  float* coll_ctx  = WS((size_t)NI*DIM);
  float* ver_ctx   = WS((size_t)NI*DIM);
  float* sub60     = WS((size_t)NI*60);
  float* gate5     = WS((size_t)NI*5);
  float* budget5   = WS((size_t)NI*5);
  float* sparse    = WS((size_t)NI*NEXPERT_);
  float* base10    = WS((size_t)NI*ODIM);
  float* reflect10 = WS((size_t)NI*ODIM);
  float* coll10    = WS((size_t)NI*ODIM);
  float* ver10     = WS((size_t)NI*ODIM);
  float* corr10    = WS((size_t)NI*ODIM);
  float* PdT       = WS((size_t)DIM*DIM);
  float* PcT       = WS((size_t)DIM*DIM);
  float* PvT       = WS((size_t)DIM*DIM);
  float* MK        = WS((size_t)NMEM_*DIM);
  // zero-initialized accumulator region (one memset)
  float* zbase     = w + off;
  float* mem_logits   = WS((size_t)NI*ODIM);
  float* depth_logits = WS((size_t)NI*ODIM);
  float* shared_pre   = WS((size_t)NI*ODIM);
  float* aux_pre      = WS((size_t)NI*ODIM);
  float* expert_pre   = WS((size_t)NEXPERT_*NI*ODIM);
  float* cum_halt     = WS((size_t)NI);
  size_t zbytes = (size_t)((w + off) - zbase) * sizeof(float);
  hipMemsetAsync((void*)zbase, 0, zbytes, stream);

  auto thin = [&](const float* A1, int K1, const float* A2, int K2,
                  const float* Wp, const float* bp, float* Cp, int NO, int post){
    int total = NI*NO;
    thin_k<<<(total+255)/256, 256, 0, stream>>>(A1,K1,A2,K2,Wp,bp,Cp,NO,post);
  };

  // ---- precompute collapsed attention matrices ----
  atb_k<<<(DIM*DIM+255)/256, 256, 0, stream>>>(depth_k_w, depth_q_w, PdT, DIM, DIM, DIM);
  atb_k<<<(DIM*DIM+255)/256, 256, 0, stream>>>(coll_k_w,  coll_q_w,  PcT, DIM, DIM, DIM);
  atb_k<<<(DIM*DIM+255)/256, 256, 0, stream>>>(ver_k_w,   ver_q_w,   PvT, DIM, DIM, DIM);
  ab_k <<<(NMEM_*DIM+255)/256, 256, 0, stream>>>(mem_keys, mem_q_w, MK, NMEM_, DIM, DIM);

  // ---- independent branches off x ----
  thin(x, DIM, nullptr, 0, Wm, bvec, base10, ODIM, 0);
  updown_k<<<dim3(3072/64, NI/64), 256, 0, stream>>>(x, shared_up_w, shared_down_w, shared_pre, 3072, 0);
  updown_k<<<dim3(4096/64, NI/64), 256, 0, stream>>>(x, aux_up_w,    aux_down_w,    aux_pre,    4096, 1);

  // ---- recurrent loop ----
  const float* cur = x;
  for (int s = 0; s < NSTEPS_; s++){
    thin(cur, DIM, nullptr, 0, MK, nullptr, mem_sc, NMEM_, 2);
    memread_k<<<NI/4, 256, 0, stream>>>(mem_sc, a_state, c_state, mem_vals, wv_hist, mem_read, s);
    thin(cur, DIM, mem_read, DIM, mem_wg_w, mem_wg_b, wg, NMEM_, 1);
    launch_gemm(1, cur, mem_wv_w, mem_wv_b, nullptr, nullptr,
                wv_hist + (size_t)s*NI*DIM, DIM, DIM, stream);
    state_k<<<(NI*NMEM_+255)/256, 256, 0, stream>>>(wg, a_state, c_state, s);
    if (s > 0){
      launch_gemm(0, cur, PdT, nullptr, nullptr, nullptr, q2, DIM, DIM, stream);
      bankattn_k<<<NI/4, 256, 0, stream>>>(q2, bank, wsumb, s);
      launch_gemm(0, wsumb, depth_v_w, nullptr, nullptr, nullptr, depth_ctx, DIM, DIM, stream);
    }
    ln3_k<<<NI/4, 256, 0, stream>>>(cur, mem_read, (s > 0 ? depth_ctx : nullptr),
                                    rc_ln_s + (size_t)s*DIM, rc_ln_b + (size_t)s*DIM,
                                    cur_in, t_ln);
    launch_gemm(2, t_ln, rc_w1 + (size_t)s*896*DIM, rc_b1 + (size_t)s*896,
                nullptr, nullptr, hbig, 896, DIM, stream);
    launch_gemm(3, hbig, rc_w2 + (size_t)s*DIM*896, rc_b2 + (size_t)s*DIM,
                cur_in, nullptr, cur_in, DIM, 896, stream);
    launch_gemm(4, cur_in, ssm_in_w, nullptr, nullptr, ssm_decay, h48, 48, DIM, stream);
    float* newcur = bank + (size_t)s*NI*DIM;
    launch_gemm(5, h48, ssm_out_w, nullptr, cur_in, nullptr, newcur, DIM, 48, stream);
    halt_k<<<NI/4, 256, 0, stream>>>(newcur, mem_read, depth_ctx, halt_w, halt_b,
                                     mem_out_w, depth_out_w, mem_logits, depth_logits,
                                     cum_halt, s);
    cur = newcur;
  }

  // ---- router ----
  thin(cur, DIM, nullptr, 0, sub_w, sub_b, sub60, 60, 0);
  thin(cur, DIM, nullptr, 0, gate_w, gate_b, gate5, 5, 0);
  thin(cur, DIM, nullptr, 0, budget_w, budget_b, budget5, 5, 0);
  router_k<<<(NI+255)/256, 256, 0, stream>>>(sub60, gate5, budget5, sparse);

  // ---- experts (dense, fused up->down) ----
  experts_k<<<dim3(MAXE/64, NI/64, NEXPERT_), 256, 0, stream>>>(cur, exp_up, exp_down, expert_pre);

  // ---- reflection (3 cells, 1280) ----
  const float* rsrc = cur;
  for (int i = 0; i < 3; i++){
    ln3_k<<<NI/4, 256, 0, stream>>>(rsrc, nullptr, nullptr,
                                    rf_ln_s + (size_t)i*DIM, rf_ln_b + (size_t)i*DIM,
                                    nullptr, t_ln);
    launch_gemm(2, t_ln, rf_w1 + (size_t)i*1280*DIM, rf_b1 + (size_t)i*1280,
                nullptr, nullptr, hbig, 1280, DIM, stream);
    launch_gemm(3, hbig, rf_w2 + (size_t)i*DIM*1280, rf_b2 + (size_t)i*DIM,
                rsrc, nullptr, rbuf, DIM, 1280, stream);
    rsrc = rbuf;
  }

  // ---- verifier (2 cells, 1536) ----
  const float* vsrc = cur;
  for (int i = 0; i < 2; i++){
    ln3_k<<<NI/4, 256, 0, stream>>>(vsrc, nullptr, nullptr,
                                    vc_ln_s + (size_t)i*DIM, vc_ln_b + (size_t)i*DIM,
                                    nullptr, t_ln);
    launch_gemm(2, t_ln, vc_w1 + (size_t)i*1536*DIM, vc_b1 + (size_t)i*1536,
                nullptr, nullptr, hbig, 1536, DIM, stream);
    launch_gemm(3, hbig, vc_w2 + (size_t)i*DIM*1536, vc_b2 + (size_t)i*DIM,
                vsrc, nullptr, vbuf, DIM, 1536, stream);
    vsrc = vbuf;
  }

  // ---- collective attention over bank ----
  launch_gemm(0, cur, PcT, nullptr, nullptr, nullptr, q2, DIM, DIM, stream);
  bankattn_k<<<NI/4, 256, 0, stream>>>(q2, bank, wsumb, NSTEPS_);
  launch_gemm(0, wsumb, coll_v_w, nullptr, nullptr, nullptr, coll_ctx, DIM, DIM, stream);

  // ---- verifier attention over bank ----
  launch_gemm(0, vbuf, PvT, nullptr, nullptr, nullptr, q2, DIM, DIM, stream);
  bankattn_k<<<NI/4, 256, 0, stream>>>(q2, bank, wsumb, NSTEPS_);
  launch_gemm(0, wsumb, ver_v_w, nullptr, nullptr, nullptr, ver_ctx, DIM, DIM, stream);

  // ---- 10-dim heads ----
  thin(rbuf,     DIM, nullptr, 0, reflect_out_w,    nullptr, reflect10, ODIM, 0);
  thin(coll_ctx, DIM, nullptr, 0, coll_out_w,       nullptr, coll10,    ODIM, 0);
  thin(ver_ctx,  DIM, nullptr, 0, ver_out_w,        nullptr, ver10,     ODIM, 0);
  thin(vbuf,     DIM, nullptr, 0, correction_out_w, nullptr, corr10,    ODIM, 0);

  // ---- final combine ----
  final_k<<<(NI+255)/256, 256, 0, stream>>>(
      x, cur, vbuf, coll_ctx, ver_ctx,
      base10, shared_pre, aux_pre, expert_pre, sparse,
      mem_logits, depth_logits, reflect10, coll10, ver10, corr10,
      shared_ln_s, shared_ln_b, aux_ln_s, aux_ln_b, exp_ln_s, exp_ln_b,
      aux_gate_w, aux_gate_b, ver_gate_w, ver_gate_b, revisit_w, revisit_b,
      shared_scale, mix, out);
}

// Round 2
// 3044.088 us; speedup vs baseline: 1.5345x; 1.5345x over previous
//
#include <hip/hip_runtime.h>

// ---------------------------------------------------------------------------
// FrontierVerifierExpertHead — round 2: bf16 MFMA for experts/shared/aux (moe_k)
// and rf/vc cells (bgemm_k). Recurrent loop + router stay fp32 (discrete
// decisions bit-identical to round 1).
// ---------------------------------------------------------------------------

constexpr int NI      = 4096;   // items
constexpr int DIM     = 256;
constexpr int ODIM    = 10;
constexpr int NMEM_   = 32;
constexpr int NSTEPS_ = 6;
constexpr int NEXPERT_= 12;
constexpr int MAXE    = 4608;
#define SCL 0.0625f             // 256^-0.5

__constant__ int EDIMS[NEXPERT_] = {2048,2560,3072,3584,4096,2304,2816,3328,3840,4608,3072,4096};

typedef __attribute__((ext_vector_type(8))) short short8v;
typedef __attribute__((ext_vector_type(4))) float float4v;
typedef __attribute__((ext_vector_type(4))) unsigned short ushort4v;

// ----------------------------- device helpers ------------------------------

__device__ __forceinline__ float wred_sum(float v){
  #pragma unroll
  for (int m = 32; m > 0; m >>= 1) v += __shfl_xor(v, m, 64);
  return v;
}
__device__ __forceinline__ float wred_max(float v){
  #pragma unroll
  for (int m = 32; m > 0; m >>= 1) v = fmaxf(v, __shfl_xor(v, m, 64));
  return v;
}
__device__ __forceinline__ float sigm(float x){ return 1.f/(1.f+expf(-x)); }
__device__ __forceinline__ float geluf(float x){ return 0.5f*x*(1.f+erff(x*0.70710678118654752f)); }
__device__ __forceinline__ float softplusf(float x){ return fmaxf(x,0.f) + log1pf(expf(-fabsf(x))); }
__device__ __forceinline__ float act_apply(int a, float x){
  switch(a){
    case 0: return x*sigm(x);                         // silu
    case 1: return geluf(x);                          // gelu (exact)
    case 2: return x*tanhf(softplusf(x));             // mish
    case 3: return fmaxf(x,0.f);                      // relu
    case 4: { const float l=1.0507009873554805f, al=1.6732632423543772f;
              return x>0.f ? l*x : l*al*expm1f(x); }  // selu
    case 5: return tanhf(x);                          // tanh
    case 6: return softplusf(x);                      // softplus
    default: return x>0.f ? x : expm1f(x);            // elu
  }
}
__device__ __forceinline__ unsigned short f2b(float f){   // fp32 -> bf16 RNE
  unsigned u = __float_as_uint(f);
  u = u + 0x7FFFu + ((u >> 16) & 1u);
  return (unsigned short)(u >> 16);
}
__device__ __forceinline__ void ln10(const float* p, const float* s, const float* b, float* o){
  float mu = 0.f;
  #pragma unroll
  for (int i=0;i<ODIM;i++) mu += p[i];
  mu *= 0.1f;
  float var = 0.f;
  #pragma unroll
  for (int i=0;i<ODIM;i++){ float d = p[i]-mu; var += d*d; }
  var *= 0.1f;
  float rs = 1.f/sqrtf(var + 1e-5f);
  #pragma unroll
  for (int i=0;i<ODIM;i++) o[i] = (p[i]-mu)*rs*s[i] + b[i];
}

// ------------------------- fp32 -> bf16 converter --------------------------
__global__ __launch_bounds__(256)
void cvt_k(const float* __restrict__ in, unsigned short* __restrict__ out, int n)
{
  int idx = (blockIdx.x*256 + threadIdx.x)*4;
  if (idx + 3 < n){
    float4 v = *(const float4*)&in[idx];
    ushort4v t; t[0]=f2b(v.x); t[1]=f2b(v.y); t[2]=f2b(v.z); t[3]=f2b(v.w);
    *(ushort4v*)&out[idx] = t;
  }
}

// ----------------------------- tiled fp32 GEMM -----------------------------
// C[4096,N] = epi(A[4096,K] @ W[N,K]^T)
// EPI: 0 none | 1 +bias | 2 gelu(+bias) | 3 +bias+R | 4 tanh(acc)*sig(vec[c]) | 5 +R
template<int EPI>
__global__ __launch_bounds__(256)
void gemm_k(const float* __restrict__ A, const float* __restrict__ W,
            const float* __restrict__ bias, const float* __restrict__ R,
            const float* __restrict__ vec, float* __restrict__ C,
            int N, int K)
{
  __shared__ float As[32][68];
  __shared__ float Ws[32][68];
  const int bm = blockIdx.y*64, bn = blockIdx.x*64;
  const int tid = threadIdx.x;
  const int tx = tid & 15, ty = tid >> 4;
  const int lrow = tid >> 2, lkq = (tid & 3) * 8;
  float acc[4][4] = {};
  for (int k0 = 0; k0 < K; k0 += 32){
    #pragma unroll
    for (int h = 0; h < 2; ++h){
      int kk = lkq + h*4;
      float4 va = make_float4(0.f,0.f,0.f,0.f), vw = make_float4(0.f,0.f,0.f,0.f);
      if (k0 + kk < K)
        va = *(const float4*)&A[(size_t)(bm+lrow)*K + k0 + kk];
      if (bn + lrow < N && k0 + kk < K)
        vw = *(const float4*)&W[(size_t)(bn+lrow)*K + k0 + kk];
      As[kk+0][lrow]=va.x; As[kk+1][lrow]=va.y; As[kk+2][lrow]=va.z; As[kk+3][lrow]=va.w;
      Ws[kk+0][lrow]=vw.x; Ws[kk+1][lrow]=vw.y; Ws[kk+2][lrow]=vw.z; Ws[kk+3][lrow]=vw.w;
    }
    __syncthreads();
    #pragma unroll
    for (int kk = 0; kk < 32; ++kk){
      float4 a4 = *(const float4*)&As[kk][ty*4];
      float4 b4 = *(const float4*)&Ws[kk][tx*4];
      float av[4] = {a4.x,a4.y,a4.z,a4.w};
      float bv[4] = {b4.x,b4.y,b4.z,b4.w};
      #pragma unroll
      for (int i=0;i<4;i++)
        #pragma unroll
        for (int j=0;j<4;j++) acc[i][j] = fmaf(av[i], bv[j], acc[i][j]);
    }
    __syncthreads();
  }
  #pragma unroll
  for (int i=0;i<4;i++){
    int r = bm + ty*4 + i;
    #pragma unroll
    for (int j=0;j<4;j++){
      int c = bn + tx*4 + j;
      if (c >= N) continue;
      float v = acc[i][j];
      if constexpr (EPI==1) v += bias[c];
      else if constexpr (EPI==2) v = geluf(v + bias[c]);
      else if constexpr (EPI==3) v = v + bias[c] + R[(size_t)r*N + c];
      else if constexpr (EPI==4) v = tanhf(v) * sigm(vec[c]);
      else if constexpr (EPI==5) v = v + R[(size_t)r*N + c];
      C[(size_t)r*N + c] = v;
    }
  }
}

// ------------------------------ bf16 MFMA GEMM -----------------------------
// C[4096,N] = epi(A_bf16[4096,K] @ B_bf16[N,K]^T)
// EPI 0: gelu(acc+bias) -> bf16 Cb ; EPI 1: acc+bias+R -> f32 Cf
template<int EPI>
__global__ __launch_bounds__(256)
void bgemm_k(const short* __restrict__ A, const short* __restrict__ B,
             const float* __restrict__ bias, const float* __restrict__ R,
             float* __restrict__ Cf, unsigned short* __restrict__ Cb,
             int N, int K)
{
  __shared__ short As[128][40];
  __shared__ short Bsm[64][40];
  const int bm = blockIdx.y*128, bn = blockIdx.x*64;
  const int tid = threadIdx.x;
  const int wave = tid >> 6, lane = tid & 63;
  const int l15 = lane & 15, lg = lane >> 4;
  const int ar = tid >> 1, ah = tid & 1;
  float4v acc[2][4] = {};
  for (int k0 = 0; k0 < K; k0 += 32){
    __syncthreads();
    { const short* src = A + (size_t)(bm+ar)*K + k0 + ah*16;
      short8v v0 = *(const short8v*)src;
      short8v v1 = *(const short8v*)(src+8);
      *(short8v*)&As[ar][ah*16]   = v0;
      *(short8v*)&As[ar][ah*16+8] = v1; }
    if (tid < 128){
      const short* src = B + (size_t)(bn+ar)*K + k0 + ah*16;
      short8v v0 = *(const short8v*)src;
      short8v v1 = *(const short8v*)(src+8);
      *(short8v*)&Bsm[ar][ah*16]   = v0;
      *(short8v*)&Bsm[ar][ah*16+8] = v1; }
    __syncthreads();
    short8v bfr[4];
    #pragma unroll
    for (int nt = 0; nt < 4; nt++)
      bfr[nt] = *(const short8v*)&Bsm[nt*16 + l15][lg*8];
    #pragma unroll
    for (int mt = 0; mt < 2; mt++){
      short8v a = *(const short8v*)&As[wave*32 + mt*16 + l15][lg*8];
      #pragma unroll
      for (int nt = 0; nt < 4; nt++)
        acc[mt][nt] = __builtin_amdgcn_mfma_f32_16x16x32_bf16(a, bfr[nt], acc[mt][nt], 0, 0, 0);
    }
  }
  #pragma unroll
  for (int mt = 0; mt < 2; mt++)
    #pragma unroll
    for (int nt = 0; nt < 4; nt++)
      #pragma unroll
      for (int reg = 0; reg < 4; reg++){
        int row = bm + wave*32 + mt*16 + lg*4 + reg;
        int col = bn + nt*16 + l15;
        float v = acc[mt][nt][reg];
        if constexpr (EPI==0){
          v = geluf(v + bias[col]);
          Cb[(size_t)row*N + col] = f2b(v);
        } else {
          v = v + bias[col] + R[(size_t)row*N + col];
          Cf[(size_t)row*N + col] = v;
        }
      }
}

// --------------- fused MoE / shared / aux up->act->down (MFMA) -------------
// z = 0..11 experts (X=cur), 12 shared (X=x, silu), 13 aux (X=x, gelu).
// Block: 512 thr (8 waves) x 128 items. Chunk loop over 64 expert cols.
__global__ __launch_bounds__(512)
void moe_k(const float* __restrict__ cur, const float* __restrict__ x,
           const float* __restrict__ exp_up, const float* __restrict__ shared_up,
           const float* __restrict__ aux_up, const short* __restrict__ upb,
           const float* __restrict__ exp_down, const float* __restrict__ shared_down,
           const float* __restrict__ aux_down,
           float* __restrict__ expert_pre, float* __restrict__ shared_pre,
           float* __restrict__ aux_pre)
{
  __shared__ short Bs[64][264];   // up chunk, +8 pad -> 2-way-free b128 reads
  __shared__ float Ds[64][12];    // down chunk transposed [ecol][o]
  const int z = blockIdx.y;
  const int bm = blockIdx.x * 128;
  const int tid = threadIdx.x;
  const int wave = tid >> 6, lane = tid & 63;
  const int l15 = lane & 15, lg = lane >> 4;

  int E, act, dstride;
  const float* upf; const short* upbz; const float* down; float* outp;
  if (z < NEXPERT_){
    E = EDIMS[z]; act = z & 7;
    upf = exp_up + (size_t)z*MAXE*DIM;
    upbz = upb ? upb + (size_t)z*MAXE*DIM : nullptr;
    down = exp_down + (size_t)z*ODIM*MAXE; dstride = MAXE;
    outp = expert_pre + (size_t)z*NI*ODIM;
  } else if (z == NEXPERT_){
    E = 3072; act = 0; upf = shared_up;
    upbz = upb ? upb + (size_t)NEXPERT_*MAXE*DIM : nullptr;
    down = shared_down; dstride = 3072; outp = shared_pre;
  } else {
    E = 4096; act = 1; upf = aux_up;
    upbz = upb ? upb + (size_t)NEXPERT_*MAXE*DIM + (size_t)3072*DIM : nullptr;
    down = aux_down; dstride = 4096; outp = aux_pre;
  }
  const float* X = (z < NEXPERT_) ? cur : x;

  // A fragments: rows bm + wave*16 + l15, k = ks*32 + lg*8 + e  (fp32 -> bf16)
  short8v afrag[8];
  {
    const float* xr = X + (size_t)(bm + wave*16 + l15)*DIM;
    #pragma unroll
    for (int ks = 0; ks < 8; ks++){
      float4 v0 = *(const float4*)&xr[ks*32 + lg*8];
      float4 v1 = *(const float4*)&xr[ks*32 + lg*8 + 4];
      short8v a;
      a[0]=(short)f2b(v0.x); a[1]=(short)f2b(v0.y); a[2]=(short)f2b(v0.z); a[3]=(short)f2b(v0.w);
      a[4]=(short)f2b(v1.x); a[5]=(short)f2b(v1.y); a[6]=(short)f2b(v1.z); a[7]=(short)f2b(v1.w);
      afrag[ks] = a;
    }
  }
  float racc[4][10];
  #pragma unroll
  for (int r = 0; r < 4; r++)
    #pragma unroll
    for (int o = 0; o < 10; o++) racc[r][o] = 0.f;

  const int sr = tid >> 3, sp = tid & 7;   // staging: row, 64B part
  for (int c = 0; c < E; c += 64){
    __syncthreads();
    if (upbz){
      const short* src = upbz + (size_t)(c + sr)*DIM + sp*32;
      short8v v0 = *(const short8v*)(src);
      short8v v1 = *(const short8v*)(src+8);
      short8v v2 = *(const short8v*)(src+16);
      short8v v3 = *(const short8v*)(src+24);
      *(short8v*)&Bs[sr][sp*32]    = v0;
      *(short8v*)&Bs[sr][sp*32+8]  = v1;
      *(short8v*)&Bs[sr][sp*32+16] = v2;
      *(short8v*)&Bs[sr][sp*32+24] = v3;
    } else {
      const float* src = upf + (size_t)(c + sr)*DIM + sp*32;
      #pragma unroll
      for (int seg = 0; seg < 4; seg++){
        float4 f0 = *(const float4*)&src[seg*8];
        float4 f1 = *(const float4*)&src[seg*8+4];
        short8v s;
        s[0]=(short)f2b(f0.x); s[1]=(short)f2b(f0.y); s[2]=(short)f2b(f0.z); s[3]=(short)f2b(f0.w);
        s[4]=(short)f2b(f1.x); s[5]=(short)f2b(f1.y); s[6]=(short)f2b(f1.z); s[7]=(short)f2b(f1.w);
        *(short8v*)&Bs[sr][sp*32+seg*8] = s;
      }
    }
    for (int t2 = tid; t2 < 640; t2 += 512){
      int e = t2 & 63, o = t2 >> 6;
      Ds[e][o] = down[(size_t)o*dstride + c + e];
    }
    __syncthreads();

    float4v acc[4] = {};
    #pragma unroll
    for (int ks = 0; ks < 8; ks++){
      #pragma unroll
      for (int nt = 0; nt < 4; nt++){
        short8v b = *(const short8v*)&Bs[nt*16 + l15][ks*32 + lg*8];
        acc[nt] = __builtin_amdgcn_mfma_f32_16x16x32_bf16(afrag[ks], b, acc[nt], 0, 0, 0);
      }
    }
    #pragma unroll
    for (int nt = 0; nt < 4; nt++){
      const float* dp = &Ds[nt*16 + l15][0];
      float4 d0 = *(const float4*)dp;
      float4 d1 = *(const float4*)(dp+4);
      float  d8 = dp[8], d9 = dp[9];
      float dv[10] = {d0.x,d0.y,d0.z,d0.w,d1.x,d1.y,d1.z,d1.w,d8,d9};
      float hv[4];
      #pragma unroll
      for (int reg = 0; reg < 4; reg++) hv[reg] = act_apply(act, acc[nt][reg]);
      #pragma unroll
      for (int o = 0; o < 10; o++)
        #pragma unroll
        for (int reg = 0; reg < 4; reg++)
          racc[reg][o] = fmaf(hv[reg], dv[o], racc[reg][o]);
    }
  }
  // reduce across the 16-lane col group; rows = bm + wave*16 + lg*4 + reg
  #pragma unroll
  for (int reg = 0; reg < 4; reg++)
    #pragma unroll
    for (int o = 0; o < 10; o++){
      float v = racc[reg][o];
      v += __shfl_xor(v, 1, 64); v += __shfl_xor(v, 2, 64);
      v += __shfl_xor(v, 4, 64); v += __shfl_xor(v, 8, 64);
      racc[reg][o] = v;
    }
  if (l15 == 0){
    #pragma unroll
    for (int reg = 0; reg < 4; reg++){
      int row = bm + wave*16 + lg*4 + reg;
      #pragma unroll
      for (int o = 0; o < 10; o++)
        outp[(size_t)row*ODIM + o] = racc[reg][o];
    }
  }
}

// --------------------------- thin per-element GEMM -------------------------
__global__ __launch_bounds__(256)
void thin_k(const float* __restrict__ A1, int K1,
            const float* __restrict__ A2, int K2,
            const float* __restrict__ W, const float* __restrict__ bias,
            float* __restrict__ C, int NO, int post)
{
  int idx = blockIdx.x*256 + threadIdx.x;
  if (idx >= NI*NO) return;
  int item = idx / NO, o = idx - item*NO;
  const float* w = W + (size_t)o*(K1+K2);
  const float* a1 = A1 + (size_t)item*K1;
  float s = 0.f;
  for (int k = 0; k < K1; k += 4){
    float4 av = *(const float4*)&a1[k];
    float4 wv = *(const float4*)&w[k];
    s = fmaf(av.x,wv.x, fmaf(av.y,wv.y, fmaf(av.z,wv.z, fmaf(av.w,wv.w, s))));
  }
  if (A2){
    const float* a2 = A2 + (size_t)item*K2;
    const float* w2 = w + K1;
    for (int k = 0; k < K2; k += 4){
      float4 av = *(const float4*)&a2[k];
      float4 wv = *(const float4*)&w2[k];
      s = fmaf(av.x,wv.x, fmaf(av.y,wv.y, fmaf(av.z,wv.z, fmaf(av.w,wv.w, s))));
    }
  }
  if (bias) s += bias[o];
  if (post == 1) s = sigm(s);
  else if (post == 2) s *= SCL;
  C[(size_t)item*NO + o] = s;
}

// ----------------------- small one-off matrix products ---------------------
__global__ void atb_k(const float* __restrict__ A, const float* __restrict__ B,
                      float* __restrict__ C, int M, int I, int J)
{ // C[i,j] = sum_m A[m,i]*B[m,j]
  int idx = blockIdx.x*256 + threadIdx.x;
  if (idx >= I*J) return;
  int i = idx / J, j = idx - i*J;
  float s = 0.f;
  for (int m = 0; m < M; m++) s = fmaf(A[(size_t)m*I+i], B[(size_t)m*J+j], s);
  C[idx] = s;
}
__global__ void ab_k(const float* __restrict__ A, const float* __restrict__ B,
                     float* __restrict__ C, int M, int K, int N)
{ // C[i,j] = sum_k A[i,k]*B[k,j]
  int idx = blockIdx.x*256 + threadIdx.x;
  if (idx >= M*N) return;
  int i = idx / N, j = idx - i*N;
  float s = 0.f;
  for (int k = 0; k < K; k++) s = fmaf(A[(size_t)i*K+k], B[(size_t)k*N+j], s);
  C[idx] = s;
}

// --------------------- LN (+up to 2 extra addends), D=256 ------------------
__global__ __launch_bounds__(256)
void ln3_k(const float* __restrict__ a, const float* __restrict__ b,
           const float* __restrict__ c, const float* __restrict__ lns,
           const float* __restrict__ lnb, float* __restrict__ xout,
           float* __restrict__ lnout, unsigned short* __restrict__ lnout_b)
{
  int item = blockIdx.x*4 + (threadIdx.x >> 6);
  int lane = threadIdx.x & 63;
  float4 v = ((const float4*)(a + (size_t)item*DIM))[lane];
  if (b){ float4 t = ((const float4*)(b + (size_t)item*DIM))[lane]; v.x+=t.x; v.y+=t.y; v.z+=t.z; v.w+=t.w; }
  if (c){ float4 t = ((const float4*)(c + (size_t)item*DIM))[lane]; v.x+=t.x; v.y+=t.y; v.z+=t.z; v.w+=t.w; }
  if (xout) ((float4*)(xout + (size_t)item*DIM))[lane] = v;
  float mu = wred_sum(v.x+v.y+v.z+v.w) * (1.f/DIM);
  float dx=v.x-mu, dy=v.y-mu, dz=v.z-mu, dw=v.w-mu;
  float var = wred_sum(dx*dx+dy*dy+dz*dz+dw*dw) * (1.f/DIM);
  float rs = 1.f/sqrtf(var + 1e-5f);
  float4 s4 = ((const float4*)lns)[lane];
  float4 b4 = ((const float4*)lnb)[lane];
  float4 o4 = make_float4(dx*rs*s4.x + b4.x, dy*rs*s4.y + b4.y,
                          dz*rs*s4.z + b4.z, dw*rs*s4.w + b4.w);
  if (lnout) ((float4*)(lnout + (size_t)item*DIM))[lane] = o4;
  if (lnout_b){
    ushort4v t; t[0]=f2b(o4.x); t[1]=f2b(o4.y); t[2]=f2b(o4.z); t[3]=f2b(o4.w);
    *(ushort4v*)(lnout_b + (size_t)item*DIM + lane*4) = t;
  }
}

// -------------------- memory read (factorized bank state) ------------------
__global__ __launch_bounds__(256)
void memread_k(const float* __restrict__ sc, const float* __restrict__ a_state,
               const float* __restrict__ c_state, const float* __restrict__ mem_vals,
               const float* __restrict__ wv_hist, float* __restrict__ mem_read, int step)
{
  int item = blockIdx.x*4 + (threadIdx.x >> 6);
  int lane = threadIdx.x & 63;
  float v = (lane < NMEM_) ? sc[(size_t)item*NMEM_ + lane] : -1e30f;
  float m = wred_max(v);
  float e = (lane < NMEM_) ? expf(v - m) : 0.f;
  float inv = 1.f / wred_sum(e);
  float attn = e * inv;
  float aval = 0.f;
  if (lane < NMEM_) aval = (step == 0) ? 1.f : a_state[(size_t)item*NMEM_ + lane];
  float wslot = attn * aval;
  float beta[NSTEPS_];
  #pragma unroll
  for (int t = 0; t < NSTEPS_; t++){
    beta[t] = 0.f;
    if (t < step){
      float cc = (lane < NMEM_) ? c_state[((size_t)item*NMEM_ + lane)*NSTEPS_ + t] : 0.f;
      beta[t] = wred_sum(attn * cc);
    }
  }
  float ax=0.f, ay=0.f, az=0.f, aw=0.f;
  #pragma unroll
  for (int s2 = 0; s2 < NMEM_; s2++){
    float ws = __shfl(wslot, s2, 64);
    float4 mv = ((const float4*)(mem_vals + (size_t)s2*DIM))[lane];
    ax = fmaf(ws, mv.x, ax); ay = fmaf(ws, mv.y, ay);
    az = fmaf(ws, mv.z, az); aw = fmaf(ws, mv.w, aw);
  }
  #pragma unroll
  for (int t = 0; t < NSTEPS_; t++){
    if (t < step){
      float4 h4 = ((const float4*)(wv_hist + ((size_t)t*NI + item)*DIM))[lane];
      ax = fmaf(beta[t], h4.x, ax); ay = fmaf(beta[t], h4.y, ay);
      az = fmaf(beta[t], h4.z, az); aw = fmaf(beta[t], h4.w, aw);
    }
  }
  ((float4*)(mem_read + (size_t)item*DIM))[lane] = make_float4(ax,ay,az,aw);
}

// ------------------------- memory state coefficient update -----------------
__global__ void state_k(const float* __restrict__ wg, float* __restrict__ a_state,
                        float* __restrict__ c_state, int step)
{
  int idx = blockIdx.x*256 + threadIdx.x;      // item*32 + slot
  if (idx >= NI*NMEM_) return;
  float g = wg[idx];
  float om = 1.f - g;
  float a = (step == 0) ? 1.f : a_state[idx];
  a_state[idx] = a * om;
  float* c = c_state + (size_t)idx*NSTEPS_;
  #pragma unroll
  for (int t = 0; t < NSTEPS_; t++) if (t < step) c[t] *= om;
  c[step] = g;
}

// ------------------- bank attention (scores+softmax+wsum) ------------------
__global__ __launch_bounds__(256)
void bankattn_k(const float* __restrict__ q2, const float* __restrict__ bank,
                float* __restrict__ wsum, int t)
{
  int item = blockIdx.x*4 + (threadIdx.x >> 6);
  int lane = threadIdx.x & 63;
  float4 q4 = ((const float4*)(q2 + (size_t)item*DIM))[lane];
  float sc[NSTEPS_];
  float4 bb[NSTEPS_];
  #pragma unroll
  for (int j = 0; j < NSTEPS_; j++){
    if (j < t){
      bb[j] = ((const float4*)(bank + ((size_t)j*NI + item)*DIM))[lane];
      sc[j] = wred_sum(q4.x*bb[j].x + q4.y*bb[j].y + q4.z*bb[j].z + q4.w*bb[j].w) * SCL;
    }
  }
  float mx = -1e30f;
  #pragma unroll
  for (int j = 0; j < NSTEPS_; j++) if (j < t) mx = fmaxf(mx, sc[j]);
  float se = 0.f;
  #pragma unroll
  for (int j = 0; j < NSTEPS_; j++) if (j < t){ sc[j] = expf(sc[j]-mx); se += sc[j]; }
  float inv = 1.f/se;
  float ax=0.f, ay=0.f, az=0.f, aw=0.f;
  #pragma unroll
  for (int j = 0; j < NSTEPS_; j++){
    if (j < t){
      float a = sc[j]*inv;
      ax = fmaf(a, bb[j].x, ax); ay = fmaf(a, bb[j].y, ay);
      az = fmaf(a, bb[j].z, az); aw = fmaf(a, bb[j].w, aw);
    }
  }
  ((float4*)(wsum + (size_t)item*DIM))[lane] = make_float4(ax,ay,az,aw);
}

// ----------------- halting + weighted 10-dim logit accumulation ------------
__global__ __launch_bounds__(256)
void halt_k(const float* __restrict__ cur, const float* __restrict__ mem_read,
            const float* __restrict__ depth_ctx, const float* __restrict__ halt_w,
            const float* __restrict__ halt_b, const float* __restrict__ mem_out_w,
            const float* __restrict__ depth_out_w, float* __restrict__ mem_logits,
            float* __restrict__ depth_logits, float* __restrict__ cum_halt, int step)
{
  int item = blockIdx.x*4 + (threadIdx.x >> 6);
  int lane = threadIdx.x & 63;
  float4 c4 = ((const float4*)(cur + (size_t)item*DIM))[lane];
  float4 hw = ((const float4*)(halt_w + (size_t)step*DIM))[lane];
  float hd = wred_sum(c4.x*hw.x + c4.y*hw.y + c4.z*hw.z + c4.w*hw.w);
  float halt = sigm(hd + halt_b[step]);
  float ch = cum_halt[item];
  float wstep = (1.f - ch) * halt;
  float4 m4 = ((const float4*)(mem_read + (size_t)item*DIM))[lane];
  float4 d4 = make_float4(0.f,0.f,0.f,0.f);
  if (step > 0) d4 = ((const float4*)(depth_ctx + (size_t)item*DIM))[lane];
  #pragma unroll
  for (int o = 0; o < ODIM; o++){
    float4 w4 = ((const float4*)(mem_out_w + (size_t)o*DIM))[lane];
    float s = wred_sum(m4.x*w4.x + m4.y*w4.y + m4.z*w4.z + m4.w*w4.w);
    if (lane == 0) mem_logits[(size_t)item*ODIM + o] += wstep * s;
    if (step > 0){
      float4 v4 = ((const float4*)(depth_out_w + (size_t)o*DIM))[lane];
      float s2 = wred_sum(d4.x*v4.x + d4.y*v4.y + d4.z*v4.z + d4.w*v4.w);
      if (lane == 0) depth_logits[(size_t)item*ODIM + o] += wstep * s2;
    }
  }
  if (lane == 0) cum_halt[item] = fminf(ch + halt, 1.f);
}

// -------------------------- router finish (per item) -----------------------
__global__ void router_k(const float* __restrict__ sub60, const float* __restrict__ gate5,
                         const float* __restrict__ budget5, float* __restrict__ sparse)
{
  int item = blockIdx.x*256 + threadIdx.x;
  if (item >= NI) return;
  float probs[NEXPERT_];
  #pragma unroll
  for (int e = 0; e < NEXPERT_; e++) probs[e] = 0.f;
  float g[5];
  float gm = -1e30f;
  #pragma unroll
  for (int s = 0; s < 5; s++){ g[s] = gate5[(size_t)item*5 + s]; gm = fmaxf(gm, g[s]); }
  float gs = 0.f;
  #pragma unroll
  for (int s = 0; s < 5; s++){ g[s] = expf(g[s]-gm); gs += g[s]; }
  float gi = 1.f/gs;
  #pragma unroll
  for (int s = 0; s < 5; s++){
    float sl[NEXPERT_];
    float mx = -1e30f;
    #pragma unroll
    for (int e = 0; e < NEXPERT_; e++){ sl[e] = sub60[(size_t)item*60 + s*NEXPERT_ + e]; mx = fmaxf(mx, sl[e]); }
    float se = 0.f;
    #pragma unroll
    for (int e = 0; e < NEXPERT_; e++){ sl[e] = expf(sl[e]-mx); se += sl[e]; }
    float w = g[s]*gi/se;
    #pragma unroll
    for (int e = 0; e < NEXPERT_; e++) probs[e] = fmaf(w, sl[e], probs[e]);
  }
  float bl0 = budget5[(size_t)item*5];
  int am = 0;
  #pragma unroll
  for (int s = 1; s < 5; s++){ float bv = budget5[(size_t)item*5 + s]; if (bv > bl0){ bl0 = bv; am = s; } }
  int kact = am + 1;
  unsigned used = 0;
  float tv[5]; int ti[5];
  float ssum = 0.f;
  #pragma unroll
  for (int j = 0; j < 5; j++){
    float bv = -1e30f; int bi = 0;
    #pragma unroll
    for (int e = 0; e < NEXPERT_; e++){
      bool ok = !((used >> e) & 1u);
      if (ok && probs[e] > bv){ bv = probs[e]; bi = e; }
    }
    used |= (1u << bi);
    tv[j] = bv; ti[j] = bi;
    if (j < kact) ssum += bv;
  }
  float den = 1.f/fmaxf(ssum, 1e-6f);
  #pragma unroll
  for (int e = 0; e < NEXPERT_; e++){
    float v = 0.f;
    #pragma unroll
    for (int j = 0; j < 5; j++) if (j < kact && ti[j] == e) v = tv[j];
    sparse[(size_t)item*NEXPERT_ + e] = v*den;
  }
}

// ------------------------------ final combine ------------------------------
__global__ void final_k(
  const float* __restrict__ x, const float* __restrict__ cur,
  const float* __restrict__ vbuf, const float* __restrict__ coll_ctx,
  const float* __restrict__ ver_ctx,
  const float* __restrict__ base10, const float* __restrict__ shared_pre,
  const float* __restrict__ aux_pre, const float* __restrict__ expert_pre,
  const float* __restrict__ sparse, const float* __restrict__ mem_logits,
  const float* __restrict__ depth_logits, const float* __restrict__ reflect10,
  const float* __restrict__ coll10, const float* __restrict__ ver10,
  const float* __restrict__ corr10,
  const float* __restrict__ shared_ln_s, const float* __restrict__ shared_ln_b,
  const float* __restrict__ aux_ln_s, const float* __restrict__ aux_ln_b,
  const float* __restrict__ exp_ln_s, const float* __restrict__ exp_ln_b,
  const float* __restrict__ aux_gate_w, const float* __restrict__ aux_gate_b,
  const float* __restrict__ ver_gate_w, const float* __restrict__ ver_gate_b,
  const float* __restrict__ revisit_w, const float* __restrict__ revisit_b,
  const float* __restrict__ shared_scale, const float* __restrict__ mix,
  float* __restrict__ out)
{
  int item = blockIdx.x*256 + threadIdx.x;
  if (item >= NI) return;
  const float* xr = x + (size_t)item*DIM;
  const float* cr = cur + (size_t)item*DIM;
  const float* vr = vbuf + (size_t)item*DIM;
  const float* lr = coll_ctx + (size_t)item*DIM;
  const float* tr = ver_ctx + (size_t)item*DIM;
  float ag0 = aux_gate_b[0], ag1 = aux_gate_b[1];
  for (int k = 0; k < DIM; k++){
    float xv = xr[k];
    ag0 = fmaf(xv, aux_gate_w[k], ag0);
    ag1 = fmaf(xv, aux_gate_w[DIM+k], ag1);
  }
  { float m = fmaxf(ag0,ag1); float e0 = expf(ag0-m), e1 = expf(ag1-m);
    float i2 = 1.f/(e0+e1); ag0 = e0*i2; ag1 = e1*i2; }
  float vg0 = ver_gate_b[0], vg1 = ver_gate_b[1];
  for (int k = 0; k < DIM; k++){
    vg0 = fmaf(vr[k], ver_gate_w[k], vg0);
    vg1 = fmaf(vr[k], ver_gate_w[512+k], vg1);
  }
  for (int k = 0; k < DIM; k++){
    vg0 = fmaf(tr[k], ver_gate_w[DIM+k], vg0);
    vg1 = fmaf(tr[k], ver_gate_w[512+DIM+k], vg1);
  }
  { float m = fmaxf(vg0,vg1); float e0 = expf(vg0-m), e1 = expf(vg1-m);
    float i2 = 1.f/(e0+e1); vg0 = e0*i2; vg1 = e1*i2; }
  float rv = revisit_b[0];
  for (int k = 0; k < DIM; k++){
    rv = fmaf(xr[k], revisit_w[k], rv);
    rv = fmaf(cr[k], revisit_w[DIM+k], rv);
    rv = fmaf(lr[k], revisit_w[2*DIM+k], rv);
  }
  rv = sigm(rv);
  float sh[ODIM], axl[ODIM];
  { float tmp[ODIM];
    #pragma unroll
    for (int o = 0; o < ODIM; o++) tmp[o] = shared_pre[(size_t)item*ODIM + o];
    ln10(tmp, shared_ln_s, shared_ln_b, sh);
    #pragma unroll
    for (int o = 0; o < ODIM; o++) tmp[o] = aux_pre[(size_t)item*ODIM + o];
    ln10(tmp, aux_ln_s, aux_ln_b, axl); }
  float eo[ODIM];
  #pragma unroll
  for (int o = 0; o < ODIM; o++) eo[o] = 0.f;
  for (int i2 = 0; i2 < NEXPERT_; i2++){
    float sp = sparse[(size_t)item*NEXPERT_ + i2];
    if (sp != 0.f){
      float tmp[ODIM], lo[ODIM];
      #pragma unroll
      for (int o = 0; o < ODIM; o++) tmp[o] = expert_pre[((size_t)i2*NI + item)*ODIM + o];
      ln10(tmp, exp_ln_s + i2*ODIM, exp_ln_b + i2*ODIM, lo);
      #pragma unroll
      for (int o = 0; o < ODIM; o++) eo[o] = fmaf(sp, lo[o], eo[o]);
    }
  }
  float al = tanhf(mix[0]), be = tanhf(mix[1]), ga = tanhf(mix[2]);
  float de = tanhf(mix[3]), ep = tanhf(mix[4]), ze = tanhf(mix[5]);
  float ss = shared_scale[0];
  #pragma unroll
  for (int o = 0; o < ODIM; o++){
    size_t ix = (size_t)item*ODIM + o;
    float v = base10[ix]
      + ss*(ag0*sh[o] + ag1*axl[o])
      + al*eo[o]
      + be*mem_logits[ix] + ze*depth_logits[ix]
      + ga*reflect10[ix]
      + de*rv*coll10[ix]
      + ep*(vg0*ver10[ix] + vg1*corr10[ix]);
    out[ix] = v;
  }
}

// ------------------------------- host side ---------------------------------

static void launch_gemm(int epi, const float* A, const float* W, const float* b,
                        const float* R, const float* vec, float* C, int N, int K,
                        hipStream_t stream)
{
  dim3 g((N+63)/64, NI/64), blk(256);
  switch(epi){
    case 0: gemm_k<0><<<g,blk,0,stream>>>(A,W,b,R,vec,C,N,K); break;
    case 1: gemm_k<1><<<g,blk,0,stream>>>(A,W,b,R,vec,C,N,K); break;
    case 2: gemm_k<2><<<g,blk,0,stream>>>(A,W,b,R,vec,C,N,K); break;
    case 3: gemm_k<3><<<g,blk,0,stream>>>(A,W,b,R,vec,C,N,K); break;
    case 4: gemm_k<4><<<g,blk,0,stream>>>(A,W,b,R,vec,C,N,K); break;
    case 5: gemm_k<5><<<g,blk,0,stream>>>(A,W,b,R,vec,C,N,K); break;
  }
}

static void launch_cvt(const float* in, unsigned short* out, size_t n, hipStream_t stream)
{
  cvt_k<<<(unsigned)((n/4 + 255)/256), 256, 0, stream>>>(in, out, (int)n);
}

extern "C" void kernel_launch(void* const* d_in, const int* in_sizes, int n_in,
                              void* d_out, int out_size, void* d_ws, size_t ws_size,
                              hipStream_t stream)
{
  (void)in_sizes; (void)n_in; (void)out_size;
  const float* x             = (const float*)d_in[0];
  const float* Wm            = (const float*)d_in[1];
  const float* bvec          = (const float*)d_in[2];
  const float* shared_up_w   = (const float*)d_in[3];
  const float* shared_down_w = (const float*)d_in[4];
  const float* shared_ln_s   = (const float*)d_in[5];
  const float* shared_ln_b   = (const float*)d_in[6];
  const float* shared_scale  = (const float*)d_in[7];
  const float* mem_keys      = (const float*)d_in[8];
  const float* mem_vals      = (const float*)d_in[9];
  const float* mem_q_w       = (const float*)d_in[10];
  const float* mem_out_w     = (const float*)d_in[11];
  const float* mem_wg_w      = (const float*)d_in[12];
  const float* mem_wg_b      = (const float*)d_in[13];
  const float* mem_wv_w      = (const float*)d_in[14];
  const float* mem_wv_b      = (const float*)d_in[15];
  const float* depth_q_w     = (const float*)d_in[16];
  const float* depth_k_w     = (const float*)d_in[17];
  const float* depth_v_w     = (const float*)d_in[18];
  const float* depth_out_w   = (const float*)d_in[19];
  const float* rc_ln_s       = (const float*)d_in[20];
  const float* rc_ln_b       = (const float*)d_in[21];
  const float* rc_w1         = (const float*)d_in[22];
  const float* rc_b1         = (const float*)d_in[23];
  const float* rc_w2         = (const float*)d_in[24];
  const float* rc_b2         = (const float*)d_in[25];
  const float* ssm_in_w      = (const float*)d_in[26];
  const float* ssm_out_w     = (const float*)d_in[27];
  const float* ssm_decay     = (const float*)d_in[28];
  const float* sub_w         = (const float*)d_in[29];
  const float* sub_b         = (const float*)d_in[30];
  const float* gate_w        = (const float*)d_in[31];
  const float* gate_b        = (const float*)d_in[32];
  const float* budget_w      = (const float*)d_in[33];
  const float* budget_b      = (const float*)d_in[34];
  const float* halt_w        = (const float*)d_in[35];
  const float* halt_b        = (const float*)d_in[36];
  const float* aux_up_w      = (const float*)d_in[37];
  const float* aux_down_w    = (const float*)d_in[38];
  const float* aux_ln_s      = (const float*)d_in[39];
  const float* aux_ln_b      = (const float*)d_in[40];
  const float* aux_gate_w    = (const float*)d_in[41];
  const float* aux_gate_b    = (const float*)d_in[42];
  const float* rf_ln_s       = (const float*)d_in[43];
  const float* rf_ln_b       = (const float*)d_in[44];
  const float* rf_w1         = (const float*)d_in[45];
  const float* rf_b1         = (const float*)d_in[46];
  const float* rf_w2         = (const float*)d_in[47];
  const float* rf_b2         = (const float*)d_in[48];
  const float* reflect_out_w = (const float*)d_in[49];
  const float* coll_q_w      = (const float*)d_in[50];
  const float* coll_k_w      = (const float*)d_in[51];
  const float* coll_v_w      = (const float*)d_in[52];
  const float* coll_out_w    = (const float*)d_in[53];
  const float* revisit_w     = (const float*)d_in[54];
  const float* revisit_b     = (const float*)d_in[55];
  const float* vc_ln_s       = (const float*)d_in[56];
  const float* vc_ln_b       = (const float*)d_in[57];
  const float* vc_w1         = (const float*)d_in[58];
  const float* vc_b1         = (const float*)d_in[59];
  const float* vc_w2         = (const float*)d_in[60];
  const float* vc_b2         = (const float*)d_in[61];
  const float* ver_q_w       = (const float*)d_in[62];
  const float* ver_k_w       = (const float*)d_in[63];
  const float* ver_v_w       = (const float*)d_in[64];
  const float* ver_out_w     = (const float*)d_in[65];
  const float* ver_gate_w    = (const float*)d_in[66];
  const float* ver_gate_b    = (const float*)d_in[67];
  const float* correction_out_w = (const float*)d_in[68];
  const float* mix           = (const float*)d_in[69];
  const float* exp_up        = (const float*)d_in[70];
  const float* exp_down      = (const float*)d_in[71];
  const float* exp_ln_s      = (const float*)d_in[72];
  const float* exp_ln_b      = (const float*)d_in[73];
  float* out = (float*)d_out;

  // ---- workspace layout (fp32 region) ----
  float* w = (float*)d_ws;
  size_t off = 0;
  auto WS = [&](size_t nf){ float* p = w + off; off += nf; return p; };
  float* bank      = WS((size_t)NSTEPS_*NI*DIM);
  float* cur_in    = WS((size_t)NI*DIM);
  float* t_ln      = WS((size_t)NI*DIM);
  float* hbig      = WS((size_t)NI*896);        // fp32 loop h; aliased below as bf16 hb
  float* mem_read  = WS((size_t)NI*DIM);
  float* depth_ctx = WS((size_t)NI*DIM);
  float* q2        = WS((size_t)NI*DIM);
  float* wsumb     = WS((size_t)NI*DIM);
  float* wv_hist   = WS((size_t)NSTEPS_*NI*DIM);
  float* wg        = WS((size_t)NI*NMEM_);
  float* mem_sc    = WS((size_t)NI*NMEM_);
  float* a_state   = WS((size_t)NI*NMEM_);
  float* c_state   = WS((size_t)NI*NMEM_*NSTEPS_);
  float* h48       = WS((size_t)NI*48);
  float* rbuf      = WS((size_t)NI*DIM);
  float* vbuf      = WS((size_t)NI*DIM);
  float* coll_ctx  = WS((size_t)NI*DIM);
  float* ver_ctx   = WS((size_t)NI*DIM);
  float* sub60     = WS((size_t)NI*60);
  float* gate5     = WS((size_t)NI*5);
  float* budget5   = WS((size_t)NI*5);
  float* sparse    = WS((size_t)NI*NEXPERT_);
  float* base10    = WS((size_t)NI*ODIM);
  float* reflect10 = WS((size_t)NI*ODIM);
  float* coll10    = WS((size_t)NI*ODIM);
  float* ver10     = WS((size_t)NI*ODIM);
  float* corr10    = WS((size_t)NI*ODIM);
  float* PdT       = WS((size_t)DIM*DIM);
  float* PcT       = WS((size_t)DIM*DIM);
  float* PvT       = WS((size_t)DIM*DIM);
  float* MK        = WS((size_t)NMEM_*DIM);
  // zero-initialized accumulator region
  float* zbase     = w + off;
  float* mem_logits   = WS((size_t)NI*ODIM);
  float* depth_logits = WS((size_t)NI*ODIM);
  float* shared_pre   = WS((size_t)NI*ODIM);
  float* aux_pre      = WS((size_t)NI*ODIM);
  float* expert_pre   = WS((size_t)NEXPERT_*NI*ODIM);
  float* cum_halt     = WS((size_t)NI);
  size_t zbytes = (size_t)((w + off) - zbase) * sizeof(float);
  hipMemsetAsync((void*)zbase, 0, zbytes, stream);

  // ---- bf16 region (after fp32 region) ----
  unsigned short* bb = (unsigned short*)(w + off);
  size_t boff = 0;
  auto BS = [&](size_t ns){ unsigned short* p = bb + boff; boff += ns; return p; };
  unsigned short* t_ln_b = BS((size_t)NI*DIM);
  unsigned short* rfw1b  = BS((size_t)3*1280*DIM);
  unsigned short* rfw2b  = BS((size_t)3*DIM*1280);
  unsigned short* vcw1b  = BS((size_t)2*1536*DIM);
  unsigned short* vcw2b  = BS((size_t)2*DIM*1536);
  unsigned short* upb    = bb + boff;              // optional big buffer
  size_t upb_n = ((size_t)NEXPERT_*MAXE + 3072 + 4096) * DIM;
  size_t base_bytes = off*sizeof(float) + boff*sizeof(unsigned short);
  bool use_upb = (ws_size >= base_bytes + upb_n*sizeof(unsigned short));
  // bf16 h-buffer for rf/vc cells aliases the fp32 loop hbig (loop finished first)
  unsigned short* hb = (unsigned short*)hbig;      // NI*1536 bf16 fits in NI*896 f32

  auto thin = [&](const float* A1, int K1, const float* A2, int K2,
                  const float* Wp, const float* bp, float* Cp, int NO, int post){
    int total = NI*NO;
    thin_k<<<(total+255)/256, 256, 0, stream>>>(A1,K1,A2,K2,Wp,bp,Cp,NO,post);
  };

  // ---- weight conversions (independent of everything) ----
  launch_cvt(rf_w1, rfw1b, (size_t)3*1280*DIM, stream);
  launch_cvt(rf_w2, rfw2b, (size_t)3*DIM*1280, stream);
  launch_cvt(vc_w1, vcw1b, (size_t)2*1536*DIM, stream);
  launch_cvt(vc_w2, vcw2b, (size_t)2*DIM*1536, stream);
  if (use_upb){
    launch_cvt(exp_up,      upb,                                    (size_t)NEXPERT_*MAXE*DIM, stream);
    launch_cvt(shared_up_w, upb + (size_t)NEXPERT_*MAXE*DIM,        (size_t)3072*DIM, stream);
    launch_cvt(aux_up_w,    upb + (size_t)NEXPERT_*MAXE*DIM + (size_t)3072*DIM, (size_t)4096*DIM, stream);
  }

  // ---- precompute collapsed attention matrices ----
  atb_k<<<(DIM*DIM+255)/256, 256, 0, stream>>>(depth_k_w, depth_q_w, PdT, DIM, DIM, DIM);
  atb_k<<<(DIM*DIM+255)/256, 256, 0, stream>>>(coll_k_w,  coll_q_w,  PcT, DIM, DIM, DIM);
  atb_k<<<(DIM*DIM+255)/256, 256, 0, stream>>>(ver_k_w,   ver_q_w,   PvT, DIM, DIM, DIM);
  ab_k <<<(NMEM_*DIM+255)/256, 256, 0, stream>>>(mem_keys, mem_q_w, MK, NMEM_, DIM, DIM);

  // ---- base head off x ----
  thin(x, DIM, nullptr, 0, Wm, bvec, base10, ODIM, 0);

  // ---- recurrent loop (fp32, unchanged) ----
  const float* cur = x;
  for (int s = 0; s < NSTEPS_; s++){
    thin(cur, DIM, nullptr, 0, MK, nullptr, mem_sc, NMEM_, 2);
    memread_k<<<NI/4, 256, 0, stream>>>(mem_sc, a_state, c_state, mem_vals, wv_hist, mem_read, s);
    thin(cur, DIM, mem_read, DIM, mem_wg_w, mem_wg_b, wg, NMEM_, 1);
    launch_gemm(1, cur, mem_wv_w, mem_wv_b, nullptr, nullptr,
                wv_hist + (size_t)s*NI*DIM, DIM, DIM, stream);
    state_k<<<(NI*NMEM_+255)/256, 256, 0, stream>>>(wg, a_state, c_state, s);
    if (s > 0){
      launch_gemm(0, cur, PdT, nullptr, nullptr, nullptr, q2, DIM, DIM, stream);
      bankattn_k<<<NI/4, 256, 0, stream>>>(q2, bank, wsumb, s);
      launch_gemm(0, wsumb, depth_v_w, nullptr, nullptr, nullptr, depth_ctx, DIM, DIM, stream);
    }
    ln3_k<<<NI/4, 256, 0, stream>>>(cur, mem_read, (s > 0 ? depth_ctx : nullptr),
                                    rc_ln_s + (size_t)s*DIM, rc_ln_b + (size_t)s*DIM,
                                    cur_in, t_ln, nullptr);
    launch_gemm(2, t_ln, rc_w1 + (size_t)s*896*DIM, rc_b1 + (size_t)s*896,
                nullptr, nullptr, hbig, 896, DIM, stream);
    launch_gemm(3, hbig, rc_w2 + (size_t)s*DIM*896, rc_b2 + (size_t)s*DIM,
                cur_in, nullptr, cur_in, DIM, 896, stream);
    launch_gemm(4, cur_in, ssm_in_w, nullptr, nullptr, ssm_decay, h48, 48, DIM, stream);
    float* newcur = bank + (size_t)s*NI*DIM;
    launch_gemm(5, h48, ssm_out_w, nullptr, cur_in, nullptr, newcur, DIM, 48, stream);
    halt_k<<<NI/4, 256, 0, stream>>>(newcur, mem_read, depth_ctx, halt_w, halt_b,
                                     mem_out_w, depth_out_w, mem_logits, depth_logits,
                                     cum_halt, s);
    cur = newcur;
  }

  // ---- router (fp32, unchanged) ----
  thin(cur, DIM, nullptr, 0, sub_w, sub_b, sub60, 60, 0);
  thin(cur, DIM, nullptr, 0, gate_w, gate_b, gate5, 5, 0);
  thin(cur, DIM, nullptr, 0, budget_w, budget_b, budget5, 5, 0);
  router_k<<<(NI+255)/256, 256, 0, stream>>>(sub60, gate5, budget5, sparse);

  // ---- experts + shared + aux (fused MFMA) ----
  moe_k<<<dim3(NI/128, NEXPERT_+2), 512, 0, stream>>>(
      cur, x, exp_up, shared_up_w, aux_up_w, use_upb ? (const short*)upb : nullptr,
      exp_down, shared_down_w, aux_down_w, expert_pre, shared_pre, aux_pre);

  // ---- reflection (3 cells, 1280, bf16 MFMA) ----
  const float* rsrc = cur;
  for (int i = 0; i < 3; i++){
    ln3_k<<<NI/4, 256, 0, stream>>>(rsrc, nullptr, nullptr,
                                    rf_ln_s + (size_t)i*DIM, rf_ln_b + (size_t)i*DIM,
                                    nullptr, nullptr, t_ln_b);
    bgemm_k<0><<<dim3(1280/64, NI/128), 256, 0, stream>>>(
        (const short*)t_ln_b, (const short*)(rfw1b + (size_t)i*1280*DIM),
        rf_b1 + (size_t)i*1280, nullptr, nullptr, hb, 1280, DIM);
    bgemm_k<1><<<dim3(DIM/64, NI/128), 256, 0, stream>>>(
        (const short*)hb, (const short*)(rfw2b + (size_t)i*DIM*1280),
        rf_b2 + (size_t)i*DIM, rsrc, rbuf, nullptr, DIM, 1280);
    rsrc = rbuf;
  }

  // ---- verifier (2 cells, 1536, bf16 MFMA) ----
  const float* vsrc = cur;
  for (int i = 0; i < 2; i++){
    ln3_k<<<NI/4, 256, 0, stream>>>(vsrc, nullptr, nullptr,
                                    vc_ln_s + (size_t)i*DIM, vc_ln_b + (size_t)i*DIM,
                                    nullptr, nullptr, t_ln_b);
    bgemm_k<0><<<dim3(1536/64, NI/128), 256, 0, stream>>>(
        (const short*)t_ln_b, (const short*)(vcw1b + (size_t)i*1536*DIM),
        vc_b1 + (size_t)i*1536, nullptr, nullptr, hb, 1536, DIM);
    bgemm_k<1><<<dim3(DIM/64, NI/128), 256, 0, stream>>>(
        (const short*)hb, (const short*)(vcw2b + (size_t)i*DIM*1536),
        vc_b2 + (size_t)i*DIM, vsrc, vbuf, nullptr, DIM, 1536);
    vsrc = vbuf;
  }

  // ---- collective attention over bank ----
  launch_gemm(0, cur, PcT, nullptr, nullptr, nullptr, q2, DIM, DIM, stream);
  bankattn_k<<<NI/4, 256, 0, stream>>>(q2, bank, wsumb, NSTEPS_);
  launch_gemm(0, wsumb, coll_v_w, nullptr, nullptr, nullptr, coll_ctx, DIM, DIM, stream);

  // ---- verifier attention over bank ----
  launch_gemm(0, vbuf, PvT, nullptr, nullptr, nullptr, q2, DIM, DIM, stream);
  bankattn_k<<<NI/4, 256, 0, stream>>>(q2, bank, wsumb, NSTEPS_);
  launch_gemm(0, wsumb, ver_v_w, nullptr, nullptr, nullptr, ver_ctx, DIM, DIM, stream);

  // ---- 10-dim heads ----
  thin(rbuf,     DIM, nullptr, 0, reflect_out_w,    nullptr, reflect10, ODIM, 0);
  thin(coll_ctx, DIM, nullptr, 0, coll_out_w,       nullptr, coll10,    ODIM, 0);
  thin(ver_ctx,  DIM, nullptr, 0, ver_out_w,        nullptr, ver10,     ODIM, 0);
  thin(vbuf,     DIM, nullptr, 0, correction_out_w, nullptr, corr10,    ODIM, 0);

  // ---- final combine ----
  final_k<<<(NI+255)/256, 256, 0, stream>>>(
      x, cur, vbuf, coll_ctx, ver_ctx,
      base10, shared_pre, aux_pre, expert_pre, sparse,
      mem_logits, depth_logits, reflect10, coll10, ver10, corr10,
      shared_ln_s, shared_ln_b, aux_ln_s, aux_ln_b, exp_ln_s, exp_ln_b,
      aux_gate_w, aux_gate_b, ver_gate_w, ver_gate_b, revisit_w, revisit_b,
      shared_scale, mix, out);
}